// Round 13
// baseline (867.688 us; speedup 1.0000x reference)
//
#include <hip/hip_runtime.h>
#include <hip/hip_bf16.h>
#include <hip/hip_fp16.h>

#define NN   50000
#define NE   800000
#define NG   64
#define DH   128
#define DOUT 5000
#define BNEPS 1e-5f
#define NBLK 196   // ceil(NN/256)
#define AGG_GRID 2048

typedef _Float16 h8 __attribute__((ext_vector_type(8)));
typedef float    f4 __attribute__((ext_vector_type(4)));

// ---------- CSR build ----------
__global__ __launch_bounds__(256) void k_count(const int* __restrict__ dst, int* __restrict__ cnt) {
    int e = blockIdx.x * 256 + threadIdx.x;
    if (e < NE) atomicAdd(&cnt[dst[e]], 1);
}

__global__ __launch_bounds__(256) void k_blkscan(const int* __restrict__ cnt, int* __restrict__ rowptr,
                                                 int* __restrict__ bsum) {
    __shared__ int s[256];
    int t = threadIdx.x, i = blockIdx.x * 256 + t;
    int v = (i < NN) ? cnt[i] : 0;
    s[t] = v;
    __syncthreads();
    for (int off = 1; off < 256; off <<= 1) {
        int x = (t >= off) ? s[t - off] : 0;
        __syncthreads();
        s[t] += x;
        __syncthreads();
    }
    if (i < NN) rowptr[i] = s[t] - v;
    if (t == 255) bsum[blockIdx.x] = s[255];
}

__global__ __launch_bounds__(256) void k_bscan(const int* __restrict__ bsum, int* __restrict__ boff) {
    __shared__ int s[256];
    int t = threadIdx.x;
    int v = (t < NBLK) ? bsum[t] : 0;
    s[t] = v;
    __syncthreads();
    for (int off = 1; off < 256; off <<= 1) {
        int x = (t >= off) ? s[t - off] : 0;
        __syncthreads();
        s[t] += x;
        __syncthreads();
    }
    if (t < NBLK) boff[t] = s[t] - v;
}

__global__ __launch_bounds__(256) void k_fin(int* __restrict__ rowptr, const int* __restrict__ boff,
                                             int* __restrict__ cnt, float* __restrict__ dis) {
    int i = blockIdx.x * 256 + threadIdx.x;
    if (i >= NN) { if (i == NN) rowptr[NN] = NE; return; }
    rowptr[i] += boff[blockIdx.x];
    dis[i] = rsqrtf((float)(cnt[i] + 1));
    cnt[i] = 0;
}

// packed edge stream: {src, weight-bits}
__global__ __launch_bounds__(256) void k_fill(const int* __restrict__ ei, const int* __restrict__ rowptr,
                                              int* __restrict__ fil, const float* __restrict__ dis,
                                              int2* __restrict__ ew) {
    int e = blockIdx.x * 256 + threadIdx.x;
    if (e >= NE) return;
    int s = ei[e], d = ei[NE + e];
    int p = rowptr[d] + atomicAdd(&fil[d], 1);
    ew[p] = make_int2(s, __float_as_int(dis[s] * dis[d]));
}

// ---------- weight prep: Wt[c][k] = (half)W[k][c] for 4 layers + gw1t ----------
__global__ __launch_bounds__(256) void k_wprep(const float* __restrict__ W0, const float* __restrict__ W1,
                                               const float* __restrict__ W2, const float* __restrict__ W3,
                                               const float* __restrict__ GW1, __half* __restrict__ Wt) {
    const float* Ws[5] = {W0, W1, W2, W3, GW1};
    int m = blockIdx.x >> 4;
    int chunk = blockIdx.x & 15;
    const float* W = Ws[m];
    __half* O = Wt + m * DH * DH;
    int ncol = (m == 4) ? 64 : DH;
    int total = ncol * DH;
    int o = chunk * 1024 + threadIdx.x;
    for (int r = 0; r < 4; r++, o += 256) {
        if (o < total) {
            int c = o >> 7, k = o & 127;
            O[o] = __float2half(W[k * ncol + c]);
        }
    }
}

// ---------- MFMA GEMM: Y(half) = bnrelu?(X) @ W  (64x128 block, 2x2 waves) ----------
// L0: Xf (fp32, no BN).  L1-3: Xh (fp16) with BN+ReLU fused.
__global__ __launch_bounds__(256) void k_gemm3(const float* __restrict__ Xf, const __half* __restrict__ Xh,
                                               const __half* __restrict__ Wt,
                                               const float* __restrict__ scale, const float* __restrict__ shift,
                                               __half* __restrict__ Y) {
    int t = threadIdx.x;
    int lane = t & 63, wid = t >> 6;
    int wr = wid >> 1, wc = wid & 1;
    int row0 = blockIdx.x * 64;
    int lr = lane & 15, lk = (lane >> 4) * 8;

    f4 acc[2][4];
#pragma unroll
    for (int i = 0; i < 2; i++)
#pragma unroll
        for (int j = 0; j < 4; j++) acc[i][j] = (f4){0.f, 0.f, 0.f, 0.f};

    for (int kt = 0; kt < 4; kt++) {
        int kbase = kt * 32 + lk;
        h8 afr[2];
#pragma unroll
        for (int fr = 0; fr < 2; fr++) {
            int gr = row0 + wr * 32 + fr * 16 + lr;
            gr = min(gr, NN - 1);
            float fv[8];
            if (Xf) {
                const float4* p = (const float4*)(Xf + (size_t)gr * DH + kbase);
                float4 v0 = p[0], v1 = p[1];
                fv[0] = v0.x; fv[1] = v0.y; fv[2] = v0.z; fv[3] = v0.w;
                fv[4] = v1.x; fv[5] = v1.y; fv[6] = v1.z; fv[7] = v1.w;
            } else {
                int4 hv = *(const int4*)(Xh + (size_t)gr * DH + kbase);
                float2 p0 = __half22float2(*(__half2*)&hv.x);
                float2 p1 = __half22float2(*(__half2*)&hv.y);
                float2 p2 = __half22float2(*(__half2*)&hv.z);
                float2 p3 = __half22float2(*(__half2*)&hv.w);
                fv[0] = p0.x; fv[1] = p0.y; fv[2] = p1.x; fv[3] = p1.y;
                fv[4] = p2.x; fv[5] = p2.y; fv[6] = p3.x; fv[7] = p3.y;
                const float4* sc4 = (const float4*)(scale + kbase);
                const float4* sh4 = (const float4*)(shift + kbase);
                float4 s0 = sc4[0], s1 = sc4[1], h0 = sh4[0], h1 = sh4[1];
                float sv[8] = {s0.x, s0.y, s0.z, s0.w, s1.x, s1.y, s1.z, s1.w};
                float hv2[8] = {h0.x, h0.y, h0.z, h0.w, h1.x, h1.y, h1.z, h1.w};
#pragma unroll
                for (int j = 0; j < 8; j++) fv[j] = fmaxf(fmaf(fv[j], sv[j], hv2[j]), 0.f);
            }
            h8 a;
#pragma unroll
            for (int j = 0; j < 8; j++) a[j] = (_Float16)fv[j];
            afr[fr] = a;
        }
#pragma unroll
        for (int fc = 0; fc < 4; fc++) {
            int gc = wc * 64 + fc * 16 + lr;
            h8 b = *(const h8*)(Wt + (size_t)gc * DH + kbase);
#pragma unroll
            for (int fr = 0; fr < 2; fr++)
                acc[fr][fc] = __builtin_amdgcn_mfma_f32_16x16x32_f16(afr[fr], b, acc[fr][fc], 0, 0, 0);
        }
    }
#pragma unroll
    for (int fr = 0; fr < 2; fr++) {
#pragma unroll
        for (int fc = 0; fc < 4; fc++) {
            int C = wc * 64 + fc * 16 + lr;
#pragma unroll
            for (int q = 0; q < 4; q++) {
                int R = row0 + wr * 32 + fr * 16 + (lane >> 4) * 4 + q;
                if (R < NN) Y[(size_t)R * DH + C] = __float2half(acc[fr][fc][q]);
            }
        }
    }
}

// ---------- aggregation (r10 form) + fused BN-finalize via last-block ticket ----------
#define EDGE(e) { int2 r = HW4[(size_t)(e).x * 32 + sl]; \
                  float w = __int_as_float((e).y); \
                  float2 g0 = __half22float2(*(__half2*)&r.x), g1 = __half22float2(*(__half2*)&r.y); \
                  a0 = fmaf(w, g0.x, a0); a1 = fmaf(w, g0.y, a1); \
                  a2 = fmaf(w, g1.x, a2); a3 = fmaf(w, g1.y, a3); }

__global__ __launch_bounds__(256) void k_agg(const __half* __restrict__ HW, const int* __restrict__ rowptr,
                                             const int2* __restrict__ EW, const float* __restrict__ dis,
                                             __half* __restrict__ OUT,
                                             float* __restrict__ ssum, float* __restrict__ ssq,
                                             const float* __restrict__ gg, const float* __restrict__ be,
                                             float* __restrict__ scale, float* __restrict__ shift,
                                             int* __restrict__ ticket) {
    __shared__ float lsum[DH], lsq[DH];
    int t = threadIdx.x;
    if (t < DH) { lsum[t] = 0.f; lsq[t] = 0.f; }
    __syncthreads();
    int wid = t >> 6, lane = t & 63;
    int sub = lane >> 5, sl = lane & 31;
    const int2* HW4 = (const int2*)HW;
    float s0 = 0, s1 = 0, s2 = 0, s3 = 0, q0 = 0, q1 = 0, q2 = 0, q3 = 0;
    int gw = blockIdx.x * 4 + wid;
    for (int i = gw * 2 + sub; i < NN; i += 16384) {
        float sd = dis[i];
        int2 hr = HW4[(size_t)i * 32 + sl];
        float2 f0 = __half22float2(*(__half2*)&hr.x);
        float2 f1 = __half22float2(*(__half2*)&hr.y);
        float wslf = sd * sd;
        float a0 = wslf * f0.x, a1 = wslf * f0.y;
        float a2 = wslf * f1.x, a3 = wslf * f1.y;
        int p = rowptr[i], p1 = rowptr[i + 1];
        for (; p + 8 <= p1; p += 8) {
            int2 e0 = EW[p], e1 = EW[p + 1], e2 = EW[p + 2], e3 = EW[p + 3];
            int2 e4 = EW[p + 4], e5 = EW[p + 5], e6 = EW[p + 6], e7 = EW[p + 7];
            EDGE(e0) EDGE(e1) EDGE(e2) EDGE(e3)
            EDGE(e4) EDGE(e5) EDGE(e6) EDGE(e7)
        }
        if (p + 4 <= p1) {
            int2 e0 = EW[p], e1 = EW[p + 1], e2 = EW[p + 2], e3 = EW[p + 3];
            EDGE(e0) EDGE(e1) EDGE(e2) EDGE(e3)
            p += 4;
        }
        for (; p < p1; p++) {
            int2 e = EW[p];
            EDGE(e)
        }
        // fp16 store of this lane's 4 feats (8B, plain)
        __half2 o01 = __floats2half2_rn(a0, a1);
        __half2 o23 = __floats2half2_rn(a2, a3);
        int i01 = *(int*)&o01, i23 = *(int*)&o23;
        long long ov = ((long long)(unsigned)i23 << 32) | (unsigned)i01;
        *(long long*)(OUT + (size_t)i * DH + sl * 4) = ov;
        s0 += a0; s1 += a1; s2 += a2; s3 += a3;
        q0 += a0 * a0; q1 += a1 * a1; q2 += a2 * a2; q3 += a3 * a3;
    }
    atomicAdd(&lsum[sl * 4 + 0], s0); atomicAdd(&lsum[sl * 4 + 1], s1);
    atomicAdd(&lsum[sl * 4 + 2], s2); atomicAdd(&lsum[sl * 4 + 3], s3);
    atomicAdd(&lsq[sl * 4 + 0], q0);  atomicAdd(&lsq[sl * 4 + 1], q1);
    atomicAdd(&lsq[sl * 4 + 2], q2);  atomicAdd(&lsq[sl * 4 + 3], q3);
    __syncthreads();
    if (t < DH) { atomicAdd(&ssum[t], lsum[t]); atomicAdd(&ssq[t], lsq[t]); }
    __syncthreads();
    __threadfence();
    __shared__ int lastS;
    if (t == 0) lastS = (atomicAdd(ticket, 1) == (int)gridDim.x - 1) ? 1 : 0;
    __syncthreads();
    if (lastS) {
        if (t < DH) {
            float sv = atomicAdd(&ssum[t], 0.f);   // coherent read-back
            float qv = atomicAdd(&ssq[t], 0.f);
            float m = sv * (1.f / NN);
            float vv = qv * (1.f / NN) - m * m;
            float r = rsqrtf(vv + BNEPS);
            float sc = r * gg[t];
            scale[t] = sc;
            shift[t] = fmaf(-m, sc, be[t]);
            ssum[t] = 0.f;
            ssq[t] = 0.f;
        }
        if (t == 0) *ticket = 0;
    }
}

// ---------- MFMA gate: gate = relu(bnrelu(H)@gw1+gb1)@gw2+gb2 (fp16 H) ----------
__global__ __launch_bounds__(256) void k_gateM(const __half* __restrict__ H, const float* __restrict__ scale,
                                               const float* __restrict__ shift, const __half* __restrict__ gw1t,
                                               const float* __restrict__ gb1, const float* __restrict__ gw2,
                                               const float* __restrict__ gb2, float* __restrict__ gate) {
    int t = threadIdx.x, lane = t & 63, w = t >> 6;
    int row0 = blockIdx.x * 64 + w * 16;
    int lr = lane & 15, lk = (lane >> 4) * 8;
    f4 acc[4];
#pragma unroll
    for (int fc = 0; fc < 4; fc++) acc[fc] = (f4){0.f, 0.f, 0.f, 0.f};

    for (int kt = 0; kt < 4; kt++) {
        int kbase = kt * 32 + lk;
        int gr = min(row0 + lr, NN - 1);
        int4 hv = *(const int4*)(H + (size_t)gr * DH + kbase);
        float2 p0 = __half22float2(*(__half2*)&hv.x);
        float2 p1 = __half22float2(*(__half2*)&hv.y);
        float2 p2 = __half22float2(*(__half2*)&hv.z);
        float2 p3 = __half22float2(*(__half2*)&hv.w);
        float fv[8] = {p0.x, p0.y, p1.x, p1.y, p2.x, p2.y, p3.x, p3.y};
        const float4* sc4 = (const float4*)(scale + kbase);
        const float4* sh4 = (const float4*)(shift + kbase);
        float4 s0 = sc4[0], s1 = sc4[1], h0 = sh4[0], h1 = sh4[1];
        float sv[8] = {s0.x, s0.y, s0.z, s0.w, s1.x, s1.y, s1.z, s1.w};
        float hv2[8] = {h0.x, h0.y, h0.z, h0.w, h1.x, h1.y, h1.z, h1.w};
        h8 a;
#pragma unroll
        for (int j = 0; j < 8; j++) a[j] = (_Float16)fmaxf(fmaf(fv[j], sv[j], hv2[j]), 0.f);
#pragma unroll
        for (int fc = 0; fc < 4; fc++) {
            h8 b = *(const h8*)(gw1t + (size_t)(fc * 16 + lr) * DH + kbase);
            acc[fc] = __builtin_amdgcn_mfma_f32_16x16x32_f16(a, b, acc[fc], 0, 0, 0);
        }
    }
    float vq[4] = {0.f, 0.f, 0.f, 0.f};
#pragma unroll
    for (int fc = 0; fc < 4; fc++) {
        float b1 = gb1[fc * 16 + lr];
        float w2 = gw2[fc * 16 + lr];
#pragma unroll
        for (int q = 0; q < 4; q++)
            vq[q] = fmaf(fmaxf(acc[fc][q] + b1, 0.f), w2, vq[q]);
    }
#pragma unroll
    for (int m = 1; m < 16; m <<= 1) {
#pragma unroll
        for (int q = 0; q < 4; q++) vq[q] += __shfl_xor(vq[q], m, 64);
    }
    if (lr == 0) {
        float b2 = gb2[0];
        int rbase = row0 + (lane >> 4) * 4;
#pragma unroll
        for (int q = 0; q < 4; q++)
            if (rbase + q < NN) gate[rbase + q] = vq[q] + b2;
    }
}

// ---------- per-group softmax stats (also zeroes pooled row) ----------
__device__ __forceinline__ int lbound(const int* __restrict__ a, int v) {
    int lo = 0, hi = NN;
    while (lo < hi) {
        int mid = (lo + hi) >> 1;
        if (a[mid] < v) lo = mid + 1; else hi = mid;
    }
    return lo;
}

__global__ __launch_bounds__(256) void k_pms(const float* __restrict__ gate, const int* __restrict__ batch,
                                             float* __restrict__ ms, float* __restrict__ pooled) {
    __shared__ float red[256];
    int g = blockIdx.x, t = threadIdx.x;
    if (t < DH) pooled[g * DH + t] = 0.f;
    int s = lbound(batch, g), e = lbound(batch, g + 1);
    float m = -INFINITY;
    for (int i = s + t; i < e; i += 256) m = fmaxf(m, gate[i]);
    red[t] = m; __syncthreads();
    for (int off = 128; off > 0; off >>= 1) { if (t < off) red[t] = fmaxf(red[t], red[t + off]); __syncthreads(); }
    m = red[0];
    __syncthreads();
    float se = 0.f;
    for (int i = s + t; i < e; i += 256) se += __expf(gate[i] - m);
    red[t] = se; __syncthreads();
    for (int off = 128; off > 0; off >>= 1) { if (t < off) red[t] += red[t + off]; __syncthreads(); }
    if (t == 0) {
        ms[g * 2] = m;
        ms[g * 2 + 1] = (e > s) ? 1.f / red[0] : 0.f;
    }
}

// ---------- node-parallel weighted pooling (BN+ReLU fused, fp16 H) ----------
#define PNODES 8
__global__ __launch_bounds__(256) void k_pool2(const __half* __restrict__ H, const float* __restrict__ scale,
                                               const float* __restrict__ shift, const float* __restrict__ gate,
                                               const int* __restrict__ batch, const float* __restrict__ ms,
                                               float* __restrict__ pooled) {
    int wid = threadIdx.x >> 6, lane = threadIdx.x & 63;
    int base = (blockIdx.x * 4 + wid) * PNODES;
    if (base >= NN) return;
    int end = min(base + PNODES, NN);
    const __half2* H2 = (const __half2*)H;
    float2 sc2 = ((const float2*)scale)[lane];
    float2 sh2 = ((const float2*)shift)[lane];
    float2 acc = make_float2(0.f, 0.f);
    int curg = batch[base];
    for (int i = base; i < end; i++) {
        int g = batch[i];
        if (g != curg) {
            atomicAdd(&pooled[curg * DH + lane * 2], acc.x);
            atomicAdd(&pooled[curg * DH + lane * 2 + 1], acc.y);
            acc = make_float2(0.f, 0.f);
            curg = g;
        }
        float a = __expf(gate[i] - ms[g * 2]) * ms[g * 2 + 1];
        float2 h = __half22float2(H2[(size_t)i * 64 + lane]);
        float hx = fmaxf(fmaf(h.x, sc2.x, sh2.x), 0.f);
        float hy = fmaxf(fmaf(h.y, sc2.y, sh2.y), 0.f);
        acc.x = fmaf(a, hx, acc.x);
        acc.y = fmaf(a, hy, acc.y);
    }
    atomicAdd(&pooled[curg * DH + lane * 2], acc.x);
    atomicAdd(&pooled[curg * DH + lane * 2 + 1], acc.y);
}

// ---------- classifier ----------
__global__ __launch_bounds__(256) void k_cls(const float* __restrict__ pooled, const float* __restrict__ cw,
                                             const float* __restrict__ cb, float* __restrict__ out) {
    __shared__ float pr[DH];
    int g = blockIdx.y;
    if (threadIdx.x < DH) pr[threadIdx.x] = pooled[g * DH + threadIdx.x];
    __syncthreads();
    int j = blockIdx.x * 256 + threadIdx.x;
    if (j >= DOUT) return;
    float acc = cb[j];
#pragma unroll 8
    for (int k = 0; k < DH; k++) acc = fmaf(pr[k], cw[k * DOUT + j], acc);
    out[g * DOUT + j] = acc;
}

extern "C" void kernel_launch(void* const* d_in, const int* in_sizes, int n_in,
                              void* d_out, int out_size, void* d_ws, size_t ws_size,
                              hipStream_t stream) {
    const float* x     = (const float*)d_in[0];
    const int*   ei    = (const int*)d_in[1];
    const int*   batch = (const int*)d_in[2];
    const float* w[4]  = {(const float*)d_in[3], (const float*)d_in[7], (const float*)d_in[11], (const float*)d_in[15]};
    const float* gg[4] = {(const float*)d_in[5], (const float*)d_in[9], (const float*)d_in[13], (const float*)d_in[17]};
    const float* be[4] = {(const float*)d_in[6], (const float*)d_in[10], (const float*)d_in[14], (const float*)d_in[18]};
    const float* gw1 = (const float*)d_in[19];
    const float* gb1 = (const float*)d_in[20];
    const float* gw2 = (const float*)d_in[21];
    const float* gb2 = (const float*)d_in[22];
    const float* cw  = (const float*)d_in[23];
    const float* cb  = (const float*)d_in[24];

    char* base = (char*)d_ws;
    size_t off = 0;
    auto take = [&](size_t n) -> char* { char* r = base + off; off = (off + n + 255) & ~(size_t)255; return r; };
    __half* bufA   = (__half*)take((size_t)NN * DH * 2);
    __half* bufB   = (__half*)take((size_t)NN * DH * 2);
    int2*  ew     = (int2*)take((size_t)NE * 8);
    int*   rowptr = (int*)take((size_t)(NN + 1) * 4);
    // contiguous zero block: cnt | stats (ssum,ssq) | ticket
    char*  zblk   = take((size_t)NN * 4 + 2 * DH * 4 + 64);
    int*   cnt    = (int*)zblk;
    float* stats  = (float*)(zblk + (size_t)NN * 4);
    float* ssum = stats, *ssq = stats + DH;
    int*   ticket = (int*)(zblk + (size_t)NN * 4 + 2 * DH * 4);
    float* dis    = (float*)take((size_t)NN * 4);
    float* gate   = (float*)take((size_t)NN * 4);
    float* scale  = (float*)take(DH * 4);
    float* shift  = (float*)take(DH * 4);
    float* pooled = (float*)take((size_t)NG * DH * 4);
    int*   bsum   = (int*)take((size_t)256 * 4);
    int*   boff   = (int*)take((size_t)256 * 4);
    float* ms     = (float*)take((size_t)NG * 2 * 4);
    __half* Wt    = (__half*)take((size_t)5 * DH * DH * 2);
    __half* gw1t  = Wt + (size_t)4 * DH * DH;

    hipMemsetAsync(zblk, 0, (size_t)NN * 4 + 2 * DH * 4 + 64, stream);
    k_count<<<(NE + 255) / 256, 256, 0, stream>>>(ei + NE, cnt);
    k_blkscan<<<NBLK, 256, 0, stream>>>(cnt, rowptr, bsum);
    k_bscan<<<1, 256, 0, stream>>>(bsum, boff);
    k_fin<<<NBLK, 256, 0, stream>>>(rowptr, boff, cnt, dis);
    k_fill<<<(NE + 255) / 256, 256, 0, stream>>>(ei, rowptr, cnt, dis, ew);
    k_wprep<<<72, 256, 0, stream>>>(w[0], w[1], w[2], w[3], gw1, Wt);

    const int gemm_grid = (NN + 63) / 64;
    for (int L = 0; L < 4; L++) {
        k_gemm3<<<gemm_grid, 256, 0, stream>>>(L == 0 ? x : nullptr, L == 0 ? nullptr : bufA,
                                               Wt + (size_t)L * DH * DH,
                                               L == 0 ? nullptr : scale,
                                               L == 0 ? nullptr : shift, bufB);
        k_agg<<<AGG_GRID, 256, 0, stream>>>(bufB, rowptr, ew, dis, bufA, ssum, ssq,
                                            gg[L], be[L], scale, shift, ticket);
    }
    k_gateM<<<(NN + 63) / 64, 256, 0, stream>>>(bufA, scale, shift, gw1t, gb1, gw2, gb2, gate);
    k_pms<<<NG, 256, 0, stream>>>(gate, batch, ms, pooled);
    k_pool2<<<(NN + 4 * PNODES - 1) / (4 * PNODES), 256, 0, stream>>>(bufA, scale, shift, gate, batch, ms, pooled);
    k_cls<<<dim3((DOUT + 255) / 256, NG), 256, 0, stream>>>(pooled, cw, cb, (float*)d_out);
}

// Round 14
// 553.669 us; speedup vs baseline: 1.5672x; 1.5672x over previous
//
#include <hip/hip_runtime.h>
#include <hip/hip_bf16.h>
#include <hip/hip_fp16.h>

#define NN   50000
#define NE   800000
#define NG   64
#define DH   128
#define DOUT 5000
#define BNEPS 1e-5f
#define NBLK 196   // ceil(NN/256)

typedef _Float16 h8 __attribute__((ext_vector_type(8)));
typedef float    f4 __attribute__((ext_vector_type(4)));

// ---------- CSR build ----------
__global__ __launch_bounds__(256) void k_count(const int* __restrict__ dst, int* __restrict__ cnt) {
    int e = blockIdx.x * 256 + threadIdx.x;
    if (e < NE) atomicAdd(&cnt[dst[e]], 1);
}

__global__ __launch_bounds__(256) void k_blkscan(const int* __restrict__ cnt, int* __restrict__ rowptr,
                                                 int* __restrict__ bsum) {
    __shared__ int s[256];
    int t = threadIdx.x, i = blockIdx.x * 256 + t;
    int v = (i < NN) ? cnt[i] : 0;
    s[t] = v;
    __syncthreads();
    for (int off = 1; off < 256; off <<= 1) {
        int x = (t >= off) ? s[t - off] : 0;
        __syncthreads();
        s[t] += x;
        __syncthreads();
    }
    if (i < NN) rowptr[i] = s[t] - v;
    if (t == 255) bsum[blockIdx.x] = s[255];
}

__global__ __launch_bounds__(256) void k_bscan(const int* __restrict__ bsum, int* __restrict__ boff) {
    __shared__ int s[256];
    int t = threadIdx.x;
    int v = (t < NBLK) ? bsum[t] : 0;
    s[t] = v;
    __syncthreads();
    for (int off = 1; off < 256; off <<= 1) {
        int x = (t >= off) ? s[t - off] : 0;
        __syncthreads();
        s[t] += x;
        __syncthreads();
    }
    if (t < NBLK) boff[t] = s[t] - v;
}

__global__ __launch_bounds__(256) void k_fin(int* __restrict__ rowptr, const int* __restrict__ boff,
                                             int* __restrict__ cnt, float* __restrict__ dis) {
    int i = blockIdx.x * 256 + threadIdx.x;
    if (i >= NN) { if (i == NN) rowptr[NN] = NE; return; }
    rowptr[i] += boff[blockIdx.x];
    dis[i] = rsqrtf((float)(cnt[i] + 1));
    cnt[i] = 0;
}

// packed edge stream: {src, weight-bits}
__global__ __launch_bounds__(256) void k_fill(const int* __restrict__ ei, const int* __restrict__ rowptr,
                                              int* __restrict__ fil, const float* __restrict__ dis,
                                              int2* __restrict__ ew) {
    int e = blockIdx.x * 256 + threadIdx.x;
    if (e >= NE) return;
    int s = ei[e], d = ei[NE + e];
    int p = rowptr[d] + atomicAdd(&fil[d], 1);
    ew[p] = make_int2(s, __float_as_int(dis[s] * dis[d]));
}

// ---------- weight prep: Wt[c][k] = (half)W[k][c] for 4 layers + gw1t ----------
__global__ __launch_bounds__(256) void k_wprep(const float* __restrict__ W0, const float* __restrict__ W1,
                                               const float* __restrict__ W2, const float* __restrict__ W3,
                                               const float* __restrict__ GW1, __half* __restrict__ Wt) {
    const float* Ws[5] = {W0, W1, W2, W3, GW1};
    int m = blockIdx.x >> 4;
    int chunk = blockIdx.x & 15;
    const float* W = Ws[m];
    __half* O = Wt + m * DH * DH;
    int ncol = (m == 4) ? 64 : DH;
    int total = ncol * DH;
    int o = chunk * 1024 + threadIdx.x;
    for (int r = 0; r < 4; r++, o += 256) {
        if (o < total) {
            int c = o >> 7, k = o & 127;
            O[o] = __float2half(W[k * ncol + c]);
        }
    }
}

// ---------- MFMA GEMM: Y(half) = bnrelu?(X) @ W  (64x128 block, 2x2 waves) ----------
// L0: Xf (fp32, no BN).  L1-3: Xh (fp16) with BN+ReLU fused.
__global__ __launch_bounds__(256) void k_gemm3(const float* __restrict__ Xf, const __half* __restrict__ Xh,
                                               const __half* __restrict__ Wt,
                                               const float* __restrict__ scale, const float* __restrict__ shift,
                                               __half* __restrict__ Y) {
    int t = threadIdx.x;
    int lane = t & 63, wid = t >> 6;
    int wr = wid >> 1, wc = wid & 1;
    int row0 = blockIdx.x * 64;
    int lr = lane & 15, lk = (lane >> 4) * 8;

    f4 acc[2][4];
#pragma unroll
    for (int i = 0; i < 2; i++)
#pragma unroll
        for (int j = 0; j < 4; j++) acc[i][j] = (f4){0.f, 0.f, 0.f, 0.f};

    for (int kt = 0; kt < 4; kt++) {
        int kbase = kt * 32 + lk;
        h8 afr[2];
#pragma unroll
        for (int fr = 0; fr < 2; fr++) {
            int gr = row0 + wr * 32 + fr * 16 + lr;
            gr = min(gr, NN - 1);
            float fv[8];
            if (Xf) {
                const float4* p = (const float4*)(Xf + (size_t)gr * DH + kbase);
                float4 v0 = p[0], v1 = p[1];
                fv[0] = v0.x; fv[1] = v0.y; fv[2] = v0.z; fv[3] = v0.w;
                fv[4] = v1.x; fv[5] = v1.y; fv[6] = v1.z; fv[7] = v1.w;
            } else {
                int4 hv = *(const int4*)(Xh + (size_t)gr * DH + kbase);
                float2 p0 = __half22float2(*(__half2*)&hv.x);
                float2 p1 = __half22float2(*(__half2*)&hv.y);
                float2 p2 = __half22float2(*(__half2*)&hv.z);
                float2 p3 = __half22float2(*(__half2*)&hv.w);
                fv[0] = p0.x; fv[1] = p0.y; fv[2] = p1.x; fv[3] = p1.y;
                fv[4] = p2.x; fv[5] = p2.y; fv[6] = p3.x; fv[7] = p3.y;
                const float4* sc4 = (const float4*)(scale + kbase);
                const float4* sh4 = (const float4*)(shift + kbase);
                float4 s0 = sc4[0], s1 = sc4[1], h0 = sh4[0], h1 = sh4[1];
                float sv[8] = {s0.x, s0.y, s0.z, s0.w, s1.x, s1.y, s1.z, s1.w};
                float hv2[8] = {h0.x, h0.y, h0.z, h0.w, h1.x, h1.y, h1.z, h1.w};
#pragma unroll
                for (int j = 0; j < 8; j++) fv[j] = fmaxf(fmaf(fv[j], sv[j], hv2[j]), 0.f);
            }
            h8 a;
#pragma unroll
            for (int j = 0; j < 8; j++) a[j] = (_Float16)fv[j];
            afr[fr] = a;
        }
#pragma unroll
        for (int fc = 0; fc < 4; fc++) {
            int gc = wc * 64 + fc * 16 + lr;
            h8 b = *(const h8*)(Wt + (size_t)gc * DH + kbase);
#pragma unroll
            for (int fr = 0; fr < 2; fr++)
                acc[fr][fc] = __builtin_amdgcn_mfma_f32_16x16x32_f16(afr[fr], b, acc[fr][fc], 0, 0, 0);
        }
    }
#pragma unroll
    for (int fr = 0; fr < 2; fr++) {
#pragma unroll
        for (int fc = 0; fc < 4; fc++) {
            int C = wc * 64 + fc * 16 + lr;
#pragma unroll
            for (int q = 0; q < 4; q++) {
                int R = row0 + wr * 32 + fr * 16 + (lane >> 4) * 4 + q;
                if (R < NN) Y[(size_t)R * DH + C] = __float2half(acc[fr][fc][q]);
            }
        }
    }
}

// ---------- aggregation: r10 form, fp16 output (plain stores), no bias, no fence ----------
#define EDGE(e) { int2 r = HW4[(size_t)(e).x * 32 + sl]; \
                  float w = __int_as_float((e).y); \
                  float2 g0 = __half22float2(*(__half2*)&r.x), g1 = __half22float2(*(__half2*)&r.y); \
                  a0 = fmaf(w, g0.x, a0); a1 = fmaf(w, g0.y, a1); \
                  a2 = fmaf(w, g1.x, a2); a3 = fmaf(w, g1.y, a3); }

__global__ __launch_bounds__(256) void k_agg(const __half* __restrict__ HW, const int* __restrict__ rowptr,
                                             const int2* __restrict__ EW, const float* __restrict__ dis,
                                             __half* __restrict__ OUT,
                                             float* __restrict__ ssum, float* __restrict__ ssq) {
    __shared__ float lsum[DH], lsq[DH];
    int t = threadIdx.x;
    if (t < DH) { lsum[t] = 0.f; lsq[t] = 0.f; }
    __syncthreads();
    int wid = t >> 6, lane = t & 63;
    int sub = lane >> 5, sl = lane & 31;
    const int2* HW4 = (const int2*)HW;
    float s0 = 0, s1 = 0, s2 = 0, s3 = 0, q0 = 0, q1 = 0, q2 = 0, q3 = 0;
    int gw = blockIdx.x * 4 + wid;
    for (int i = gw * 2 + sub; i < NN; i += 16384) {
        float sd = dis[i];
        int2 hr = HW4[(size_t)i * 32 + sl];
        float2 f0 = __half22float2(*(__half2*)&hr.x);
        float2 f1 = __half22float2(*(__half2*)&hr.y);
        float wslf = sd * sd;
        float a0 = wslf * f0.x, a1 = wslf * f0.y;
        float a2 = wslf * f1.x, a3 = wslf * f1.y;
        int p = rowptr[i], p1 = rowptr[i + 1];
        for (; p + 8 <= p1; p += 8) {
            int2 e0 = EW[p], e1 = EW[p + 1], e2 = EW[p + 2], e3 = EW[p + 3];
            int2 e4 = EW[p + 4], e5 = EW[p + 5], e6 = EW[p + 6], e7 = EW[p + 7];
            EDGE(e0) EDGE(e1) EDGE(e2) EDGE(e3)
            EDGE(e4) EDGE(e5) EDGE(e6) EDGE(e7)
        }
        if (p + 4 <= p1) {
            int2 e0 = EW[p], e1 = EW[p + 1], e2 = EW[p + 2], e3 = EW[p + 3];
            EDGE(e0) EDGE(e1) EDGE(e2) EDGE(e3)
            p += 4;
        }
        for (; p < p1; p++) {
            int2 e = EW[p];
            EDGE(e)
        }
        __half2 o01 = __floats2half2_rn(a0, a1);
        __half2 o23 = __floats2half2_rn(a2, a3);
        int i01 = *(int*)&o01, i23 = *(int*)&o23;
        long long ov = ((long long)(unsigned)i23 << 32) | (unsigned)i01;
        *(long long*)(OUT + (size_t)i * DH + sl * 4) = ov;
        s0 += a0; s1 += a1; s2 += a2; s3 += a3;
        q0 += a0 * a0; q1 += a1 * a1; q2 += a2 * a2; q3 += a3 * a3;
    }
    atomicAdd(&lsum[sl * 4 + 0], s0); atomicAdd(&lsum[sl * 4 + 1], s1);
    atomicAdd(&lsum[sl * 4 + 2], s2); atomicAdd(&lsum[sl * 4 + 3], s3);
    atomicAdd(&lsq[sl * 4 + 0], q0);  atomicAdd(&lsq[sl * 4 + 1], q1);
    atomicAdd(&lsq[sl * 4 + 2], q2);  atomicAdd(&lsq[sl * 4 + 3], q3);
    __syncthreads();
    if (t < DH) { atomicAdd(&ssum[t], lsum[t]); atomicAdd(&ssq[t], lsq[t]); }
}

__global__ void k_bnfin(float* __restrict__ ssum, float* __restrict__ ssq,
                        const float* __restrict__ g, const float* __restrict__ be,
                        float* __restrict__ scale, float* __restrict__ shift) {
    int f = threadIdx.x;
    float m = ssum[f] * (1.f / NN);
    float v = ssq[f] * (1.f / NN) - m * m;
    float r = rsqrtf(v + BNEPS);
    float sc = r * g[f];
    scale[f] = sc;
    shift[f] = fmaf(-m, sc, be[f]);
    ssum[f] = 0.f;
    ssq[f] = 0.f;
}

// ---------- MFMA gate: gate = relu(bnrelu(H)@gw1+gb1)@gw2+gb2 (fp16 H) ----------
__global__ __launch_bounds__(256) void k_gateM(const __half* __restrict__ H, const float* __restrict__ scale,
                                               const float* __restrict__ shift, const __half* __restrict__ gw1t,
                                               const float* __restrict__ gb1, const float* __restrict__ gw2,
                                               const float* __restrict__ gb2, float* __restrict__ gate) {
    int t = threadIdx.x, lane = t & 63, w = t >> 6;
    int row0 = blockIdx.x * 64 + w * 16;
    int lr = lane & 15, lk = (lane >> 4) * 8;
    f4 acc[4];
#pragma unroll
    for (int fc = 0; fc < 4; fc++) acc[fc] = (f4){0.f, 0.f, 0.f, 0.f};

    for (int kt = 0; kt < 4; kt++) {
        int kbase = kt * 32 + lk;
        int gr = min(row0 + lr, NN - 1);
        int4 hv = *(const int4*)(H + (size_t)gr * DH + kbase);
        float2 p0 = __half22float2(*(__half2*)&hv.x);
        float2 p1 = __half22float2(*(__half2*)&hv.y);
        float2 p2 = __half22float2(*(__half2*)&hv.z);
        float2 p3 = __half22float2(*(__half2*)&hv.w);
        float fv[8] = {p0.x, p0.y, p1.x, p1.y, p2.x, p2.y, p3.x, p3.y};
        const float4* sc4 = (const float4*)(scale + kbase);
        const float4* sh4 = (const float4*)(shift + kbase);
        float4 s0 = sc4[0], s1 = sc4[1], h0 = sh4[0], h1 = sh4[1];
        float sv[8] = {s0.x, s0.y, s0.z, s0.w, s1.x, s1.y, s1.z, s1.w};
        float hv2[8] = {h0.x, h0.y, h0.z, h0.w, h1.x, h1.y, h1.z, h1.w};
        h8 a;
#pragma unroll
        for (int j = 0; j < 8; j++) a[j] = (_Float16)fmaxf(fmaf(fv[j], sv[j], hv2[j]), 0.f);
#pragma unroll
        for (int fc = 0; fc < 4; fc++) {
            h8 b = *(const h8*)(gw1t + (size_t)(fc * 16 + lr) * DH + kbase);
            acc[fc] = __builtin_amdgcn_mfma_f32_16x16x32_f16(a, b, acc[fc], 0, 0, 0);
        }
    }
    float vq[4] = {0.f, 0.f, 0.f, 0.f};
#pragma unroll
    for (int fc = 0; fc < 4; fc++) {
        float b1 = gb1[fc * 16 + lr];
        float w2 = gw2[fc * 16 + lr];
#pragma unroll
        for (int q = 0; q < 4; q++)
            vq[q] = fmaf(fmaxf(acc[fc][q] + b1, 0.f), w2, vq[q]);
    }
#pragma unroll
    for (int m = 1; m < 16; m <<= 1) {
#pragma unroll
        for (int q = 0; q < 4; q++) vq[q] += __shfl_xor(vq[q], m, 64);
    }
    if (lr == 0) {
        float b2 = gb2[0];
        int rbase = row0 + (lane >> 4) * 4;
#pragma unroll
        for (int q = 0; q < 4; q++)
            if (rbase + q < NN) gate[rbase + q] = vq[q] + b2;
    }
}

// ---------- per-group softmax stats (also zeroes pooled row) ----------
__device__ __forceinline__ int lbound(const int* __restrict__ a, int v) {
    int lo = 0, hi = NN;
    while (lo < hi) {
        int mid = (lo + hi) >> 1;
        if (a[mid] < v) lo = mid + 1; else hi = mid;
    }
    return lo;
}

__global__ __launch_bounds__(256) void k_pms(const float* __restrict__ gate, const int* __restrict__ batch,
                                             float* __restrict__ ms, float* __restrict__ pooled) {
    __shared__ float red[256];
    int g = blockIdx.x, t = threadIdx.x;
    if (t < DH) pooled[g * DH + t] = 0.f;
    int s = lbound(batch, g), e = lbound(batch, g + 1);
    float m = -INFINITY;
    for (int i = s + t; i < e; i += 256) m = fmaxf(m, gate[i]);
    red[t] = m; __syncthreads();
    for (int off = 128; off > 0; off >>= 1) { if (t < off) red[t] = fmaxf(red[t], red[t + off]); __syncthreads(); }
    m = red[0];
    __syncthreads();
    float se = 0.f;
    for (int i = s + t; i < e; i += 256) se += __expf(gate[i] - m);
    red[t] = se; __syncthreads();
    for (int off = 128; off > 0; off >>= 1) { if (t < off) red[t] += red[t + off]; __syncthreads(); }
    if (t == 0) {
        ms[g * 2] = m;
        ms[g * 2 + 1] = (e > s) ? 1.f / red[0] : 0.f;
    }
}

// ---------- node-parallel weighted pooling (BN+ReLU fused, fp16 H) ----------
#define PNODES 8
__global__ __launch_bounds__(256) void k_pool2(const __half* __restrict__ H, const float* __restrict__ scale,
                                               const float* __restrict__ shift, const float* __restrict__ gate,
                                               const int* __restrict__ batch, const float* __restrict__ ms,
                                               float* __restrict__ pooled) {
    int wid = threadIdx.x >> 6, lane = threadIdx.x & 63;
    int base = (blockIdx.x * 4 + wid) * PNODES;
    if (base >= NN) return;
    int end = min(base + PNODES, NN);
    const __half2* H2 = (const __half2*)H;
    float2 sc2 = ((const float2*)scale)[lane];
    float2 sh2 = ((const float2*)shift)[lane];
    float2 acc = make_float2(0.f, 0.f);
    int curg = batch[base];
    for (int i = base; i < end; i++) {
        int g = batch[i];
        if (g != curg) {
            atomicAdd(&pooled[curg * DH + lane * 2], acc.x);
            atomicAdd(&pooled[curg * DH + lane * 2 + 1], acc.y);
            acc = make_float2(0.f, 0.f);
            curg = g;
        }
        float a = __expf(gate[i] - ms[g * 2]) * ms[g * 2 + 1];
        float2 h = __half22float2(H2[(size_t)i * 64 + lane]);
        float hx = fmaxf(fmaf(h.x, sc2.x, sh2.x), 0.f);
        float hy = fmaxf(fmaf(h.y, sc2.y, sh2.y), 0.f);
        acc.x = fmaf(a, hx, acc.x);
        acc.y = fmaf(a, hy, acc.y);
    }
    atomicAdd(&pooled[curg * DH + lane * 2], acc.x);
    atomicAdd(&pooled[curg * DH + lane * 2 + 1], acc.y);
}

// ---------- classifier ----------
__global__ __launch_bounds__(256) void k_cls(const float* __restrict__ pooled, const float* __restrict__ cw,
                                             const float* __restrict__ cb, float* __restrict__ out) {
    __shared__ float pr[DH];
    int g = blockIdx.y;
    if (threadIdx.x < DH) pr[threadIdx.x] = pooled[g * DH + threadIdx.x];
    __syncthreads();
    int j = blockIdx.x * 256 + threadIdx.x;
    if (j >= DOUT) return;
    float acc = cb[j];
#pragma unroll 8
    for (int k = 0; k < DH; k++) acc = fmaf(pr[k], cw[k * DOUT + j], acc);
    out[g * DOUT + j] = acc;
}

extern "C" void kernel_launch(void* const* d_in, const int* in_sizes, int n_in,
                              void* d_out, int out_size, void* d_ws, size_t ws_size,
                              hipStream_t stream) {
    const float* x     = (const float*)d_in[0];
    const int*   ei    = (const int*)d_in[1];
    const int*   batch = (const int*)d_in[2];
    const float* w[4]  = {(const float*)d_in[3], (const float*)d_in[7], (const float*)d_in[11], (const float*)d_in[15]};
    const float* gg[4] = {(const float*)d_in[5], (const float*)d_in[9], (const float*)d_in[13], (const float*)d_in[17]};
    const float* be[4] = {(const float*)d_in[6], (const float*)d_in[10], (const float*)d_in[14], (const float*)d_in[18]};
    const float* gw1 = (const float*)d_in[19];
    const float* gb1 = (const float*)d_in[20];
    const float* gw2 = (const float*)d_in[21];
    const float* gb2 = (const float*)d_in[22];
    const float* cw  = (const float*)d_in[23];
    const float* cb  = (const float*)d_in[24];

    char* base = (char*)d_ws;
    size_t off = 0;
    auto take = [&](size_t n) -> char* { char* r = base + off; off = (off + n + 255) & ~(size_t)255; return r; };
    __half* bufA   = (__half*)take((size_t)NN * DH * 2);
    __half* bufB   = (__half*)take((size_t)NN * DH * 2);
    int2*  ew     = (int2*)take((size_t)NE * 8);
    int*   rowptr = (int*)take((size_t)(NN + 1) * 4);
    // contiguous zero block: cnt | stats (ssum,ssq)
    char*  zblk   = take((size_t)NN * 4 + 2 * DH * 4);
    int*   cnt    = (int*)zblk;
    float* stats  = (float*)(zblk + (size_t)NN * 4);
    float* ssum = stats, *ssq = stats + DH;
    float* dis    = (float*)take((size_t)NN * 4);
    float* gate   = (float*)take((size_t)NN * 4);
    float* scale  = (float*)take(DH * 4);
    float* shift  = (float*)take(DH * 4);
    float* pooled = (float*)take((size_t)NG * DH * 4);
    int*   bsum   = (int*)take((size_t)256 * 4);
    int*   boff   = (int*)take((size_t)256 * 4);
    float* ms     = (float*)take((size_t)NG * 2 * 4);
    __half* Wt    = (__half*)take((size_t)5 * DH * DH * 2);
    __half* gw1t  = Wt + (size_t)4 * DH * DH;

    hipMemsetAsync(zblk, 0, (size_t)NN * 4 + 2 * DH * 4, stream);
    k_count<<<(NE + 255) / 256, 256, 0, stream>>>(ei + NE, cnt);
    k_blkscan<<<NBLK, 256, 0, stream>>>(cnt, rowptr, bsum);
    k_bscan<<<1, 256, 0, stream>>>(bsum, boff);
    k_fin<<<NBLK, 256, 0, stream>>>(rowptr, boff, cnt, dis);
    k_fill<<<(NE + 255) / 256, 256, 0, stream>>>(ei, rowptr, cnt, dis, ew);
    k_wprep<<<72, 256, 0, stream>>>(w[0], w[1], w[2], w[3], gw1, Wt);

    const int gemm_grid = (NN + 63) / 64;
    for (int L = 0; L < 4; L++) {
        k_gemm3<<<gemm_grid, 256, 0, stream>>>(L == 0 ? x : nullptr, L == 0 ? nullptr : bufA,
                                               Wt + (size_t)L * DH * DH,
                                               L == 0 ? nullptr : scale,
                                               L == 0 ? nullptr : shift, bufB);
        k_agg<<<2048, 256, 0, stream>>>(bufB, rowptr, ew, dis, bufA, ssum, ssq);
        k_bnfin<<<1, DH, 0, stream>>>(ssum, ssq, gg[L], be[L], scale, shift);
    }
    k_gateM<<<(NN + 63) / 64, 256, 0, stream>>>(bufA, scale, shift, gw1t, gb1, gw2, gb2, gate);
    k_pms<<<NG, 256, 0, stream>>>(gate, batch, ms, pooled);
    k_pool2<<<(NN + 4 * PNODES - 1) / (4 * PNODES), 256, 0, stream>>>(bufA, scale, shift, gate, batch, ms, pooled);
    k_cls<<<dim3((DOUT + 255) / 256, NG), 256, 0, stream>>>(pooled, cw, cb, (float*)d_out);
}

// Round 15
// 535.416 us; speedup vs baseline: 1.6206x; 1.0341x over previous
//
#include <hip/hip_runtime.h>
#include <hip/hip_bf16.h>
#include <hip/hip_fp16.h>

#define NN   50000
#define NE   800000
#define NG   64
#define DH   128
#define DOUT 5000
#define BNEPS 1e-5f
#define NBLK 196   // ceil(NN/256)

typedef _Float16 h8 __attribute__((ext_vector_type(8)));
typedef float    f4 __attribute__((ext_vector_type(4)));

// ---------- CSR build ----------
__global__ __launch_bounds__(256) void k_count(const int* __restrict__ dst, int* __restrict__ cnt) {
    int e = blockIdx.x * 256 + threadIdx.x;
    if (e < NE) atomicAdd(&cnt[dst[e]], 1);
}

__global__ __launch_bounds__(256) void k_blkscan(const int* __restrict__ cnt, int* __restrict__ rowptr,
                                                 int* __restrict__ bsum) {
    __shared__ int s[256];
    int t = threadIdx.x, i = blockIdx.x * 256 + t;
    int v = (i < NN) ? cnt[i] : 0;
    s[t] = v;
    __syncthreads();
    for (int off = 1; off < 256; off <<= 1) {
        int x = (t >= off) ? s[t - off] : 0;
        __syncthreads();
        s[t] += x;
        __syncthreads();
    }
    if (i < NN) rowptr[i] = s[t] - v;
    if (t == 255) bsum[blockIdx.x] = s[255];
}

// fin with folded block-sum scan (each block re-scans bsum locally)
__global__ __launch_bounds__(256) void k_fin(int* __restrict__ rowptr, const int* __restrict__ bsum,
                                             int* __restrict__ cnt, float* __restrict__ dis) {
    __shared__ int s[256];
    int t = threadIdx.x;
    int v = (t < NBLK) ? bsum[t] : 0;
    s[t] = v;
    __syncthreads();
    for (int off = 1; off < 256; off <<= 1) {
        int x = (t >= off) ? s[t - off] : 0;
        __syncthreads();
        s[t] += x;
        __syncthreads();
    }
    int excl = s[t] - v;
    __syncthreads();
    s[t] = excl;
    __syncthreads();
    int off0 = s[blockIdx.x];
    int i = blockIdx.x * 256 + t;
    if (i >= NN) { if (i == NN) rowptr[NN] = NE; return; }
    rowptr[i] += off0;
    dis[i] = rsqrtf((float)(cnt[i] + 1));
    cnt[i] = 0;
}

// packed edge stream: {src, weight-bits}
__global__ __launch_bounds__(256) void k_fill(const int* __restrict__ ei, const int* __restrict__ rowptr,
                                              int* __restrict__ fil, const float* __restrict__ dis,
                                              int2* __restrict__ ew) {
    int e = blockIdx.x * 256 + threadIdx.x;
    if (e >= NE) return;
    int s = ei[e], d = ei[NE + e];
    int p = rowptr[d] + atomicAdd(&fil[d], 1);
    ew[p] = make_int2(s, __float_as_int(dis[s] * dis[d]));
}

// ---------- weight prep: Wt[c][k] = (half)W[k][c] for 4 layers + gw1t ----------
__global__ __launch_bounds__(256) void k_wprep(const float* __restrict__ W0, const float* __restrict__ W1,
                                               const float* __restrict__ W2, const float* __restrict__ W3,
                                               const float* __restrict__ GW1, __half* __restrict__ Wt) {
    const float* Ws[5] = {W0, W1, W2, W3, GW1};
    int m = blockIdx.x >> 4;
    int chunk = blockIdx.x & 15;
    const float* W = Ws[m];
    __half* O = Wt + m * DH * DH;
    int ncol = (m == 4) ? 64 : DH;
    int total = ncol * DH;
    int o = chunk * 1024 + threadIdx.x;
    for (int r = 0; r < 4; r++, o += 256) {
        if (o < total) {
            int c = o >> 7, k = o & 127;
            O[o] = __float2half(W[k * ncol + c]);
        }
    }
}

// ---------- MFMA GEMM: Y(half) = bnrelu?(X) @ W  (64x128 block, 2x2 waves) ----------
// L0: Xf (fp32, stats==null).  L1-3: Xh (fp16), BN scale/shift derived in-block from stats.
__global__ __launch_bounds__(256) void k_gemm3(const float* __restrict__ Xf, const __half* __restrict__ Xh,
                                               const __half* __restrict__ Wt,
                                               const float* __restrict__ stats, const float* __restrict__ gg,
                                               const float* __restrict__ be, __half* __restrict__ Y) {
    __shared__ float ssc[DH], ssh[DH];
    int t = threadIdx.x;
    if (stats) {
        if (t < DH) {
            float m = stats[t] * (1.f / NN);
            float vv = stats[DH + t] * (1.f / NN) - m * m;
            float r = rsqrtf(vv + BNEPS);
            float sc = r * gg[t];
            ssc[t] = sc;
            ssh[t] = fmaf(-m, sc, be[t]);
        }
        __syncthreads();
    }
    int lane = t & 63, wid = t >> 6;
    int wr = wid >> 1, wc = wid & 1;
    int row0 = blockIdx.x * 64;
    int lr = lane & 15, lk = (lane >> 4) * 8;

    f4 acc[2][4];
#pragma unroll
    for (int i = 0; i < 2; i++)
#pragma unroll
        for (int j = 0; j < 4; j++) acc[i][j] = (f4){0.f, 0.f, 0.f, 0.f};

    for (int kt = 0; kt < 4; kt++) {
        int kbase = kt * 32 + lk;
        h8 afr[2];
#pragma unroll
        for (int fr = 0; fr < 2; fr++) {
            int gr = row0 + wr * 32 + fr * 16 + lr;
            gr = min(gr, NN - 1);
            float fv[8];
            if (Xf) {
                const float4* p = (const float4*)(Xf + (size_t)gr * DH + kbase);
                float4 v0 = p[0], v1 = p[1];
                fv[0] = v0.x; fv[1] = v0.y; fv[2] = v0.z; fv[3] = v0.w;
                fv[4] = v1.x; fv[5] = v1.y; fv[6] = v1.z; fv[7] = v1.w;
            } else {
                int4 hv = *(const int4*)(Xh + (size_t)gr * DH + kbase);
                float2 p0 = __half22float2(*(__half2*)&hv.x);
                float2 p1 = __half22float2(*(__half2*)&hv.y);
                float2 p2 = __half22float2(*(__half2*)&hv.z);
                float2 p3 = __half22float2(*(__half2*)&hv.w);
                fv[0] = p0.x; fv[1] = p0.y; fv[2] = p1.x; fv[3] = p1.y;
                fv[4] = p2.x; fv[5] = p2.y; fv[6] = p3.x; fv[7] = p3.y;
#pragma unroll
                for (int j = 0; j < 8; j++)
                    fv[j] = fmaxf(fmaf(fv[j], ssc[kbase + j], ssh[kbase + j]), 0.f);
            }
            h8 a;
#pragma unroll
            for (int j = 0; j < 8; j++) a[j] = (_Float16)fv[j];
            afr[fr] = a;
        }
#pragma unroll
        for (int fc = 0; fc < 4; fc++) {
            int gc = wc * 64 + fc * 16 + lr;
            h8 b = *(const h8*)(Wt + (size_t)gc * DH + kbase);
#pragma unroll
            for (int fr = 0; fr < 2; fr++)
                acc[fr][fc] = __builtin_amdgcn_mfma_f32_16x16x32_f16(afr[fr], b, acc[fr][fc], 0, 0, 0);
        }
    }
#pragma unroll
    for (int fr = 0; fr < 2; fr++) {
#pragma unroll
        for (int fc = 0; fc < 4; fc++) {
            int C = wc * 64 + fc * 16 + lr;
#pragma unroll
            for (int q = 0; q < 4; q++) {
                int R = row0 + wr * 32 + fr * 16 + (lane >> 4) * 4 + q;
                if (R < NN) Y[(size_t)R * DH + C] = __float2half(acc[fr][fc][q]);
            }
        }
    }
}

// ---------- aggregation: r14 proven form (fp16 out, plain stores, no bias) ----------
#define EDGE(e) { int2 r = HW4[(size_t)(e).x * 32 + sl]; \
                  float w = __int_as_float((e).y); \
                  float2 g0 = __half22float2(*(__half2*)&r.x), g1 = __half22float2(*(__half2*)&r.y); \
                  a0 = fmaf(w, g0.x, a0); a1 = fmaf(w, g0.y, a1); \
                  a2 = fmaf(w, g1.x, a2); a3 = fmaf(w, g1.y, a3); }

__global__ __launch_bounds__(256) void k_agg(const __half* __restrict__ HW, const int* __restrict__ rowptr,
                                             const int2* __restrict__ EW, const float* __restrict__ dis,
                                             __half* __restrict__ OUT, float* __restrict__ stats) {
    __shared__ float lsum[DH], lsq[DH];
    int t = threadIdx.x;
    if (t < DH) { lsum[t] = 0.f; lsq[t] = 0.f; }
    __syncthreads();
    int wid = t >> 6, lane = t & 63;
    int sub = lane >> 5, sl = lane & 31;
    const int2* HW4 = (const int2*)HW;
    float s0 = 0, s1 = 0, s2 = 0, s3 = 0, q0 = 0, q1 = 0, q2 = 0, q3 = 0;
    int gw = blockIdx.x * 4 + wid;
    for (int i = gw * 2 + sub; i < NN; i += 16384) {
        float sd = dis[i];
        int2 hr = HW4[(size_t)i * 32 + sl];
        float2 f0 = __half22float2(*(__half2*)&hr.x);
        float2 f1 = __half22float2(*(__half2*)&hr.y);
        float wslf = sd * sd;
        float a0 = wslf * f0.x, a1 = wslf * f0.y;
        float a2 = wslf * f1.x, a3 = wslf * f1.y;
        int p = rowptr[i], p1 = rowptr[i + 1];
        for (; p + 8 <= p1; p += 8) {
            int2 e0 = EW[p], e1 = EW[p + 1], e2 = EW[p + 2], e3 = EW[p + 3];
            int2 e4 = EW[p + 4], e5 = EW[p + 5], e6 = EW[p + 6], e7 = EW[p + 7];
            EDGE(e0) EDGE(e1) EDGE(e2) EDGE(e3)
            EDGE(e4) EDGE(e5) EDGE(e6) EDGE(e7)
        }
        if (p + 4 <= p1) {
            int2 e0 = EW[p], e1 = EW[p + 1], e2 = EW[p + 2], e3 = EW[p + 3];
            EDGE(e0) EDGE(e1) EDGE(e2) EDGE(e3)
            p += 4;
        }
        for (; p < p1; p++) {
            int2 e = EW[p];
            EDGE(e)
        }
        __half2 o01 = __floats2half2_rn(a0, a1);
        __half2 o23 = __floats2half2_rn(a2, a3);
        int i01 = *(int*)&o01, i23 = *(int*)&o23;
        long long ov = ((long long)(unsigned)i23 << 32) | (unsigned)i01;
        *(long long*)(OUT + (size_t)i * DH + sl * 4) = ov;
        s0 += a0; s1 += a1; s2 += a2; s3 += a3;
        q0 += a0 * a0; q1 += a1 * a1; q2 += a2 * a2; q3 += a3 * a3;
    }
    atomicAdd(&lsum[sl * 4 + 0], s0); atomicAdd(&lsum[sl * 4 + 1], s1);
    atomicAdd(&lsum[sl * 4 + 2], s2); atomicAdd(&lsum[sl * 4 + 3], s3);
    atomicAdd(&lsq[sl * 4 + 0], q0);  atomicAdd(&lsq[sl * 4 + 1], q1);
    atomicAdd(&lsq[sl * 4 + 2], q2);  atomicAdd(&lsq[sl * 4 + 3], q3);
    __syncthreads();
    if (t < DH) { atomicAdd(&stats[t], lsum[t]); atomicAdd(&stats[DH + t], lsq[t]); }
}

// ---------- MFMA gate (fp16 H, BN derived in-block) ----------
__global__ __launch_bounds__(256) void k_gateM(const __half* __restrict__ H, const float* __restrict__ stats,
                                               const float* __restrict__ gg, const float* __restrict__ be,
                                               const __half* __restrict__ gw1t,
                                               const float* __restrict__ gb1, const float* __restrict__ gw2,
                                               const float* __restrict__ gb2, float* __restrict__ gate) {
    __shared__ float ssc[DH], ssh[DH];
    int t = threadIdx.x;
    if (t < DH) {
        float m = stats[t] * (1.f / NN);
        float vv = stats[DH + t] * (1.f / NN) - m * m;
        float r = rsqrtf(vv + BNEPS);
        float sc = r * gg[t];
        ssc[t] = sc;
        ssh[t] = fmaf(-m, sc, be[t]);
    }
    __syncthreads();
    int lane = t & 63, w = t >> 6;
    int row0 = blockIdx.x * 64 + w * 16;
    int lr = lane & 15, lk = (lane >> 4) * 8;
    f4 acc[4];
#pragma unroll
    for (int fc = 0; fc < 4; fc++) acc[fc] = (f4){0.f, 0.f, 0.f, 0.f};

    for (int kt = 0; kt < 4; kt++) {
        int kbase = kt * 32 + lk;
        int gr = min(row0 + lr, NN - 1);
        int4 hv = *(const int4*)(H + (size_t)gr * DH + kbase);
        float2 p0 = __half22float2(*(__half2*)&hv.x);
        float2 p1 = __half22float2(*(__half2*)&hv.y);
        float2 p2 = __half22float2(*(__half2*)&hv.z);
        float2 p3 = __half22float2(*(__half2*)&hv.w);
        float fv[8] = {p0.x, p0.y, p1.x, p1.y, p2.x, p2.y, p3.x, p3.y};
        h8 a;
#pragma unroll
        for (int j = 0; j < 8; j++)
            a[j] = (_Float16)fmaxf(fmaf(fv[j], ssc[kbase + j], ssh[kbase + j]), 0.f);
#pragma unroll
        for (int fc = 0; fc < 4; fc++) {
            h8 b = *(const h8*)(gw1t + (size_t)(fc * 16 + lr) * DH + kbase);
            acc[fc] = __builtin_amdgcn_mfma_f32_16x16x32_f16(a, b, acc[fc], 0, 0, 0);
        }
    }
    float vq[4] = {0.f, 0.f, 0.f, 0.f};
#pragma unroll
    for (int fc = 0; fc < 4; fc++) {
        float b1 = gb1[fc * 16 + lr];
        float w2 = gw2[fc * 16 + lr];
#pragma unroll
        for (int q = 0; q < 4; q++)
            vq[q] = fmaf(fmaxf(acc[fc][q] + b1, 0.f), w2, vq[q]);
    }
#pragma unroll
    for (int m = 1; m < 16; m <<= 1) {
#pragma unroll
        for (int q = 0; q < 4; q++) vq[q] += __shfl_xor(vq[q], m, 64);
    }
    if (lr == 0) {
        float b2 = gb2[0];
        int rbase = row0 + (lane >> 4) * 4;
#pragma unroll
        for (int q = 0; q < 4; q++)
            if (rbase + q < NN) gate[rbase + q] = vq[q] + b2;
    }
}

// ---------- per-group softmax stats (also zeroes pooled row) ----------
__device__ __forceinline__ int lbound(const int* __restrict__ a, int v) {
    int lo = 0, hi = NN;
    while (lo < hi) {
        int mid = (lo + hi) >> 1;
        if (a[mid] < v) lo = mid + 1; else hi = mid;
    }
    return lo;
}

__global__ __launch_bounds__(256) void k_pms(const float* __restrict__ gate, const int* __restrict__ batch,
                                             float* __restrict__ ms, float* __restrict__ pooled) {
    __shared__ float red[256];
    int g = blockIdx.x, t = threadIdx.x;
    if (t < DH) pooled[g * DH + t] = 0.f;
    int s = lbound(batch, g), e = lbound(batch, g + 1);
    float m = -INFINITY;
    for (int i = s + t; i < e; i += 256) m = fmaxf(m, gate[i]);
    red[t] = m; __syncthreads();
    for (int off = 128; off > 0; off >>= 1) { if (t < off) red[t] = fmaxf(red[t], red[t + off]); __syncthreads(); }
    m = red[0];
    __syncthreads();
    float se = 0.f;
    for (int i = s + t; i < e; i += 256) se += __expf(gate[i] - m);
    red[t] = se; __syncthreads();
    for (int off = 128; off > 0; off >>= 1) { if (t < off) red[t] += red[t + off]; __syncthreads(); }
    if (t == 0) {
        ms[g * 2] = m;
        ms[g * 2 + 1] = (e > s) ? 1.f / red[0] : 0.f;
    }
}

// ---------- node-parallel weighted pooling (fp16 H, BN derived per-thread) ----------
#define PNODES 8
__global__ __launch_bounds__(256) void k_pool2(const __half* __restrict__ H, const float* __restrict__ stats,
                                               const float* __restrict__ gg, const float* __restrict__ be,
                                               const float* __restrict__ gate,
                                               const int* __restrict__ batch, const float* __restrict__ ms,
                                               float* __restrict__ pooled) {
    int wid = threadIdx.x >> 6, lane = threadIdx.x & 63;
    int base = (blockIdx.x * 4 + wid) * PNODES;
    if (base >= NN) return;
    int f0 = lane * 2, f1 = lane * 2 + 1;
    float m0 = stats[f0] * (1.f / NN), m1 = stats[f1] * (1.f / NN);
    float v0 = stats[DH + f0] * (1.f / NN) - m0 * m0;
    float v1 = stats[DH + f1] * (1.f / NN) - m1 * m1;
    float r0 = rsqrtf(v0 + BNEPS) * gg[f0], r1 = rsqrtf(v1 + BNEPS) * gg[f1];
    float2 sc2 = make_float2(r0, r1);
    float2 sh2 = make_float2(fmaf(-m0, r0, be[f0]), fmaf(-m1, r1, be[f1]));
    int end = min(base + PNODES, NN);
    const __half2* H2 = (const __half2*)H;
    float2 acc = make_float2(0.f, 0.f);
    int curg = batch[base];
    for (int i = base; i < end; i++) {
        int g = batch[i];
        if (g != curg) {
            atomicAdd(&pooled[curg * DH + lane * 2], acc.x);
            atomicAdd(&pooled[curg * DH + lane * 2 + 1], acc.y);
            acc = make_float2(0.f, 0.f);
            curg = g;
        }
        float a = __expf(gate[i] - ms[g * 2]) * ms[g * 2 + 1];
        float2 h = __half22float2(H2[(size_t)i * 64 + lane]);
        float hx = fmaxf(fmaf(h.x, sc2.x, sh2.x), 0.f);
        float hy = fmaxf(fmaf(h.y, sc2.y, sh2.y), 0.f);
        acc.x = fmaf(a, hx, acc.x);
        acc.y = fmaf(a, hy, acc.y);
    }
    atomicAdd(&pooled[curg * DH + lane * 2], acc.x);
    atomicAdd(&pooled[curg * DH + lane * 2 + 1], acc.y);
}

// ---------- classifier ----------
__global__ __launch_bounds__(256) void k_cls(const float* __restrict__ pooled, const float* __restrict__ cw,
                                             const float* __restrict__ cb, float* __restrict__ out) {
    __shared__ float pr[DH];
    int g = blockIdx.y;
    if (threadIdx.x < DH) pr[threadIdx.x] = pooled[g * DH + threadIdx.x];
    __syncthreads();
    int j = blockIdx.x * 256 + threadIdx.x;
    if (j >= DOUT) return;
    float acc = cb[j];
#pragma unroll 8
    for (int k = 0; k < DH; k++) acc = fmaf(pr[k], cw[k * DOUT + j], acc);
    out[g * DOUT + j] = acc;
}

extern "C" void kernel_launch(void* const* d_in, const int* in_sizes, int n_in,
                              void* d_out, int out_size, void* d_ws, size_t ws_size,
                              hipStream_t stream) {
    const float* x     = (const float*)d_in[0];
    const int*   ei    = (const int*)d_in[1];
    const int*   batch = (const int*)d_in[2];
    const float* w[4]  = {(const float*)d_in[3], (const float*)d_in[7], (const float*)d_in[11], (const float*)d_in[15]};
    const float* gg[4] = {(const float*)d_in[5], (const float*)d_in[9], (const float*)d_in[13], (const float*)d_in[17]};
    const float* be[4] = {(const float*)d_in[6], (const float*)d_in[10], (const float*)d_in[14], (const float*)d_in[18]};
    const float* gw1 = (const float*)d_in[19];
    const float* gb1 = (const float*)d_in[20];
    const float* gw2 = (const float*)d_in[21];
    const float* gb2 = (const float*)d_in[22];
    const float* cw  = (const float*)d_in[23];
    const float* cb  = (const float*)d_in[24];

    char* base = (char*)d_ws;
    size_t off = 0;
    auto take = [&](size_t n) -> char* { char* r = base + off; off = (off + n + 255) & ~(size_t)255; return r; };
    __half* bufA   = (__half*)take((size_t)NN * DH * 2);
    __half* bufB   = (__half*)take((size_t)NN * DH * 2);
    int2*  ew     = (int2*)take((size_t)NE * 8);
    int*   rowptr = (int*)take((size_t)(NN + 1) * 4);
    // contiguous zero block: cnt | stats x4 layers (ssum,ssq each)
    char*  zblk   = take((size_t)NN * 4 + 4 * 2 * DH * 4);
    int*   cnt    = (int*)zblk;
    float* statsL = (float*)(zblk + (size_t)NN * 4);
    float* dis    = (float*)take((size_t)NN * 4);
    float* gate   = (float*)take((size_t)NN * 4);
    float* pooled = (float*)take((size_t)NG * DH * 4);
    int*   bsum   = (int*)take((size_t)256 * 4);
    float* ms     = (float*)take((size_t)NG * 2 * 4);
    __half* Wt    = (__half*)take((size_t)5 * DH * DH * 2);
    __half* gw1t  = Wt + (size_t)4 * DH * DH;

    hipMemsetAsync(zblk, 0, (size_t)NN * 4 + 4 * 2 * DH * 4, stream);
    k_count<<<(NE + 255) / 256, 256, 0, stream>>>(ei + NE, cnt);
    k_blkscan<<<NBLK, 256, 0, stream>>>(cnt, rowptr, bsum);
    k_fin<<<NBLK, 256, 0, stream>>>(rowptr, bsum, cnt, dis);
    k_fill<<<(NE + 255) / 256, 256, 0, stream>>>(ei, rowptr, cnt, dis, ew);
    k_wprep<<<72, 256, 0, stream>>>(w[0], w[1], w[2], w[3], gw1, Wt);

    const int gemm_grid = (NN + 63) / 64;
    for (int L = 0; L < 4; L++) {
        k_gemm3<<<gemm_grid, 256, 0, stream>>>(L == 0 ? x : nullptr, L == 0 ? nullptr : bufA,
                                               Wt + (size_t)L * DH * DH,
                                               L == 0 ? nullptr : statsL + (size_t)(L - 1) * 2 * DH,
                                               L == 0 ? nullptr : gg[L - 1],
                                               L == 0 ? nullptr : be[L - 1], bufB);
        k_agg<<<2048, 256, 0, stream>>>(bufB, rowptr, ew, dis, bufA, statsL + (size_t)L * 2 * DH);
    }
    k_gateM<<<(NN + 63) / 64, 256, 0, stream>>>(bufA, statsL + 3 * 2 * DH, gg[3], be[3],
                                                gw1t, gb1, gw2, gb2, gate);
    k_pms<<<NG, 256, 0, stream>>>(gate, batch, ms, pooled);
    k_pool2<<<(NN + 4 * PNODES - 1) / (4 * PNODES), 256, 0, stream>>>(bufA, statsL + 3 * 2 * DH, gg[3], be[3],
                                                                      gate, batch, ms, pooled);
    k_cls<<<dim3((DOUT + 255) / 256, NG), 256, 0, stream>>>(pooled, cw, cb, (float*)d_out);
}